// Round 1
// baseline (474.174 us; speedup 1.0000x reference)
//
#include <hip/hip_runtime.h>

#define NPATH 4864
#define YDIM  25
#define NW    259
#define NCG   1225

// Persistent device-global CG table + W-decode table, rewritten every launch
// by setup_kernel (cheap, deterministic, graph-capture safe).
__device__ float g_cg[NCG];
__device__ int   g_wtab[NW * 2];

__device__ __forceinline__ double dfact(int n) {
    double f = 1.0;
    for (int i = 2; i <= n; ++i) f *= (double)i;
    return f;
}
__device__ __forceinline__ int iabs_(int x) { return x < 0 ? -x : x; }
__device__ __forceinline__ int imax3(int a, int b, int c) { int m = a > b ? a : b; return m > c ? m : c; }
__device__ __forceinline__ int imin3(int a, int b, int c) { int m = a < b ? a : b; return m < c ? m : c; }

__device__ double wig3j(int j1, int j2, int j3, int m1, int m2, int m3) {
    if (m1 + m2 + m3 != 0) return 0.0;
    if (iabs_(m1) > j1 || iabs_(m2) > j2 || iabs_(m3) > j3) return 0.0;
    if (j3 < iabs_(j1 - j2) || j3 > j1 + j2) return 0.0;
    double pre = sqrt(dfact(j1 + j2 - j3) * dfact(j1 - j2 + j3) * dfact(-j1 + j2 + j3)
                      / dfact(j1 + j2 + j3 + 1));
    pre *= sqrt(dfact(j1 + m1) * dfact(j1 - m1) * dfact(j2 + m2) * dfact(j2 - m2)
                * dfact(j3 + m3) * dfact(j3 - m3));
    int t0 = imax3(0, j2 - j3 - m1, j1 - j3 + m2);
    int t1 = imin3(j1 + j2 - j3, j1 - m1, j2 + m2);
    double s = 0.0;
    for (int t = t0; t <= t1; ++t) {
        double d = dfact(t) * dfact(j3 - j2 + m1 + t) * dfact(j3 - j1 - m2 + t)
                 * dfact(j1 + j2 - j3 - t) * dfact(j1 - m1 - t) * dfact(j2 + m2 - t);
        s += ((t & 1) ? -1.0 : 1.0) / d;
    }
    int p = j1 - j2 - m3;
    p = ((p % 2) + 2) % 2;
    return (p ? -1.0 : 1.0) * pre * s;
}

// real_to_complex: A[M+l, m+l], complex Y^M in real SH basis
__device__ void fill_A(int l, double* Are, double* Aim) {
    int n = 2 * l + 1;
    for (int i = 0; i < n * n; ++i) { Are[i] = 0.0; Aim[i] = 0.0; }
    Are[l * n + l] = 1.0;
    double s2 = sqrt(0.5);
    for (int m = 1; m <= l; ++m) {
        double sgn = (m & 1) ? -1.0 : 1.0;
        Are[(l + m) * n + (l + m)] = sgn * s2;   // (-1)^m / sqrt2
        Aim[(l + m) * n + (l - m)] = sgn * s2;   // 1j*(-1)^m / sqrt2
        Are[(l - m) * n + (l + m)] = s2;         // 1/sqrt2
        Aim[(l - m) * n + (l - m)] = -s2;        // -1j/sqrt2
    }
}

// One block per (l1,l2,l3) combo; computes real CG tensor (unit Frobenius norm),
// exactly replicating the reference construction, in fp64.
__global__ __launch_bounds__(64) void setup_kernel() {
    const int CL1[19]  = {0,0,0,1,1,1,1,1,1,1,2,2,2,2,2,2,2,2,2};
    const int CL2[19]  = {0,1,2,0,1,1,1,2,2,2,0,1,1,1,2,2,2,2,2};
    const int CL3[19]  = {0,1,2,1,0,1,2,1,2,3,2,1,2,3,0,1,2,3,4};
    const int COFF[19] = {0,1,10,35,44,53,80,125,170,245,350,375,420,495,600,625,700,825,1000};

    int c = blockIdx.x;
    int t = threadIdx.x;

    // W decode table: flat w -> (cg row offset, lf). Order matches W layout.
    if (c == 0 && t == 63) {
        const int NLFt[9]   = {1,1,1,1,3,3,1,3,5};
        const int CGOFF9[9] = {0,1,10,35,44,125,350,375,600};
        int w = 0;
        for (int ij = 0; ij < 9; ++ij) {
            int lo = ij / 3, li = ij % 3;
            int lfmin = lo > li ? lo - li : li - lo;
            int no2 = 2 * lo + 1, ni2 = 2 * li + 1;
            int cgo = CGOFF9[ij];
            for (int k = 0; k < NLFt[ij]; ++k) {
                int lf = lfmin + k;
                for (int a = 0; a < no2; ++a)
                    for (int b = 0; b < ni2; ++b) {
                        g_wtab[2 * w]     = cgo + (a * ni2 + b) * (2 * lf + 1);
                        g_wtab[2 * w + 1] = lf;
                        ++w;
                    }
                cgo += no2 * ni2 * (2 * lf + 1);
            }
        }
    }

    int l1 = CL1[c], l2 = CL2[c], l3 = CL3[c], coff = COFF[c];
    int n1 = 2 * l1 + 1, n2 = 2 * l2 + 1, n3 = 2 * l3 + 1;

    __shared__ double A1re[25], A1im[25], A2re[25], A2im[25], A3re[81], A3im[81];
    __shared__ double Tm[25];
    __shared__ double Cre[225], Cim[225];
    __shared__ double redR[64], redI[64];

    if (t == 0)      fill_A(l1, A1re, A1im);
    else if (t == 1) fill_A(l2, A2re, A2im);
    else if (t == 2) fill_A(l3, A3re, A3im);
    else if (t == 3) {
        for (int a = 0; a < n1; ++a)
            for (int b = 0; b < n2; ++b) {
                int m1 = a - l1, m2 = b - l2, m3 = -(m1 + m2);
                Tm[a * n2 + b] = (iabs_(m3) <= l3) ? wig3j(l1, l2, l3, m1, m2, m3) : 0.0;
            }
    }
    __syncthreads();

    int ntot = n1 * n2 * n3;
    double sre = 0.0, sim = 0.0;
    for (int idx = t; idx < ntot; idx += 64) {
        int i3 = idx % n3;
        int r  = idx / n3;
        int i2 = r % n2;
        int i1 = r / n2;
        double ar = 0.0, ai = 0.0;
        for (int a = 0; a < n1; ++a) {
            double x1r = A1re[a * n1 + i1], x1i = -A1im[a * n1 + i1];
            for (int b = 0; b < n2; ++b) {
                double tv = Tm[a * n2 + b];
                if (tv == 0.0) continue;
                int m3 = -((a - l1) + (b - l2));
                if (iabs_(m3) > l3) continue;
                double x2r = A2re[b * n2 + i2], x2i = -A2im[b * n2 + i2];
                double x3r = A3re[(m3 + l3) * n3 + i3], x3i = -A3im[(m3 + l3) * n3 + i3];
                double pr = x1r * x2r - x1i * x2i;
                double pi = x1r * x2i + x1i * x2r;
                double qr = pr * x3r - pi * x3i;
                double qi = pr * x3i + pi * x3r;
                ar += tv * qr;
                ai += tv * qi;
            }
        }
        Cre[idx] = ar; Cim[idx] = ai;
        sre += ar * ar; sim += ai * ai;
    }
    redR[t] = sre; redI[t] = sim;
    __syncthreads();
    if (t == 0) {
        double a = 0.0, b = 0.0;
        for (int q = 0; q < 64; ++q) { a += redR[q]; b += redI[q]; }
        redR[0] = a; redI[0] = b;
    }
    __syncthreads();
    double totR = redR[0], totI = redI[0];
    bool useRe = (totR >= totI);
    double nn  = sqrt(useRe ? totR : totI);
    double inv = (nn > 0.0) ? 1.0 / nn : 0.0;
    for (int idx = t; idx < ntot; idx += 64)
        g_cg[coff + idx] = (float)((useRe ? Cre[idx] : Cim[idx]) * inv);
}

// Per-column block compute: fixed (j, v, b) per thread; W cached in registers.
template <int LO, int LI, int NLF_>
__device__ __forceinline__ void do_block(const float* __restrict__ Wl,
                                         const float* __restrict__ Rl,
                                         float nrm, float* __restrict__ outcol,
                                         int v, int b, int woff, int roff, int rowbase) {
    constexpr int NO2 = 2 * LO + 1, NI2 = 2 * LI + 1;
    float Wreg[NLF_ * NO2];
#pragma unroll
    for (int k = 0; k < NLF_; ++k)
#pragma unroll
        for (int a = 0; a < NO2; ++a)
            Wreg[k * NO2 + a] = Wl[woff + (k * NO2 + a) * NI2 + b];
#pragma unroll 4
    for (int u = 0; u < 16; ++u) {
        int rb = roff + (u * 16 + v) * NLF_;
        float Rk[NLF_];
#pragma unroll
        for (int k = 0; k < NLF_; ++k) Rk[k] = Rl[rb + k];
        float* orow = outcol + (rowbase + u * NO2) * 144;
#pragma unroll
        for (int a = 0; a < NO2; ++a) {
            float acc = 0.f;
#pragma unroll
            for (int k = 0; k < NLF_; ++k) acc += Wreg[k * NO2 + a] * Rk[k];
            orow[a * 144] = nrm * acc;
        }
    }
}

__global__ __launch_bounds__(256) void tp_kernel(const float* __restrict__ Yg,
                                                 const float* __restrict__ Rg,
                                                 const float* __restrict__ Ng,
                                                 float* __restrict__ Og, int batch) {
    __shared__ __align__(16) float Rl[NPATH];
    __shared__ float Wl[NW];
    __shared__ float Ys[YDIM];

    int z = blockIdx.x;
    int t = threadIdx.x;

    // Stage R[z,:] coalesced as float4 (19456 B row, 16B-aligned).
    const float4* Rg4 = (const float4*)(Rg + (size_t)z * NPATH);
    float4* Rl4 = (float4*)Rl;
    for (int p = t; p < NPATH / 4; p += 256) Rl4[p] = Rg4[p];
    if (t < YDIM) Ys[t] = Yg[t * batch + z];   // Y is [25, batch]
    __syncthreads();

    // W[w] = sum_c cg[row_w, c] * Y[lf^2 + c, z]  (259 values)
    for (int w = t; w < NW; w += 256) {
        int off = g_wtab[2 * w], lf = g_wtab[2 * w + 1];
        float acc = 0.f;
        for (int ci = 0; ci <= 2 * lf; ++ci) acc += g_cg[off + ci] * Ys[lf * lf + ci];
        Wl[w] = acc;
    }
    __syncthreads();

    if (t >= 144) return;   // after last barrier; safe

    // Decode column -> (j, v, b)
    int j, v, b;
    if (t < 16)      { j = 0; v = t; b = 0; }
    else if (t < 64) { int q = t - 16; j = 1; v = q / 3; b = q - 3 * v; }
    else             { int q = t - 64; j = 2; v = q / 5; b = q - 5 * v; }

    float* outcol = Og + (size_t)z * 20736 + t;
    float n0 = Ng[(0 * 3 + j) * batch + z];
    float n1 = Ng[(1 * 3 + j) * batch + z];
    float n2 = Ng[(2 * 3 + j) * batch + z];

    if (j == 0) {
        do_block<0, 0, 1>(Wl, Rl, n0, outcol, v, b,   0,    0,  0);
        do_block<1, 0, 1>(Wl, Rl, n1, outcol, v, b,   9,  768, 16);
        do_block<2, 0, 1>(Wl, Rl, n2, outcol, v, b,  84, 2560, 64);
    } else if (j == 1) {
        do_block<0, 1, 1>(Wl, Rl, n0, outcol, v, b,   1,  256,  0);
        do_block<1, 1, 3>(Wl, Rl, n1, outcol, v, b,  12, 1024, 16);
        do_block<2, 1, 3>(Wl, Rl, n2, outcol, v, b,  89, 2816, 64);
    } else {
        do_block<0, 2, 1>(Wl, Rl, n0, outcol, v, b,   4,  512,  0);
        do_block<1, 2, 3>(Wl, Rl, n1, outcol, v, b,  39, 1792, 16);
        do_block<2, 2, 5>(Wl, Rl, n2, outcol, v, b, 134, 3584, 64);
    }
}

extern "C" void kernel_launch(void* const* d_in, const int* in_sizes, int n_in,
                              void* d_out, int out_size, void* d_ws, size_t ws_size,
                              hipStream_t stream) {
    const float* Y = (const float*)d_in[0];
    const float* R = (const float*)d_in[1];
    const float* N = (const float*)d_in[2];
    float* O = (float*)d_out;
    int batch = in_sizes[0] / YDIM;   // 4096

    hipLaunchKernelGGL(setup_kernel, dim3(19), dim3(64), 0, stream);
    hipLaunchKernelGGL(tp_kernel, dim3(batch), dim3(256), 0, stream, Y, R, N, O, batch);
}

// Round 2
// 420.233 us; speedup vs baseline: 1.1284x; 1.1284x over previous
//
#include <hip/hip_runtime.h>

#define NPATH 4864
#define YDIM  25
#define NW    259
#define NCG   1225

// ---------------- compile-time CG tables ----------------

struct Tables {
    float cg[NCG];   // per-combo flattened [a][b][c] CG tensors, unit Frobenius norm
    int   woff[NW];  // W decode: cg row offset
    int   wlf[NW];   // W decode: l_filter
};

constexpr double cfact(int n) { double f = 1.0; for (int i = 2; i <= n; ++i) f *= (double)i; return f; }

constexpr double csqrt_(double x) {
    if (x <= 0.0) return 0.0;
    double g = x > 1.0 ? x : 1.0, p = 0.0;
    for (int it = 0; it < 200; ++it) { p = g; g = 0.5 * (g + x / g); if (g == p) break; }
    return g;
}
constexpr int cabs_(int x) { return x < 0 ? -x : x; }
constexpr int cmax3(int a, int b, int c) { int m = a > b ? a : b; return m > c ? m : c; }
constexpr int cmin3(int a, int b, int c) { int m = a < b ? a : b; return m < c ? m : c; }

constexpr double cwig3j(int j1, int j2, int j3, int m1, int m2, int m3) {
    if (m1 + m2 + m3 != 0) return 0.0;
    if (cabs_(m1) > j1 || cabs_(m2) > j2 || cabs_(m3) > j3) return 0.0;
    if (j3 < cabs_(j1 - j2) || j3 > j1 + j2) return 0.0;
    double prod = cfact(j1 + j2 - j3) * cfact(j1 - j2 + j3) * cfact(-j1 + j2 + j3)
                / cfact(j1 + j2 + j3 + 1);
    prod *= cfact(j1 + m1) * cfact(j1 - m1) * cfact(j2 + m2) * cfact(j2 - m2)
          * cfact(j3 + m3) * cfact(j3 - m3);
    double pre = csqrt_(prod);
    int t0 = cmax3(0, j2 - j3 - m1, j1 - j3 + m2);
    int t1 = cmin3(j1 + j2 - j3, j1 - m1, j2 + m2);
    double s = 0.0;
    for (int t = t0; t <= t1; ++t) {
        double d = cfact(t) * cfact(j3 - j2 + m1 + t) * cfact(j3 - j1 - m2 + t)
                 * cfact(j1 + j2 - j3 - t) * cfact(j1 - m1 - t) * cfact(j2 + m2 - t);
        s += ((t & 1) ? -1.0 : 1.0) / d;
    }
    int p = j1 - j2 - m3; p = ((p % 2) + 2) % 2;
    return (p ? -1.0 : 1.0) * pre * s;
}

struct Ent { int col; double re; double im; };

// Row a of real_to_complex(l): complex Y^M (M=a-l) in the real basis; <=2 nonzeros.
constexpr int arow(int l, int a, Ent* e) {
    int m = a - l;
    double s2 = csqrt_(0.5);
    if (m == 0) { e[0] = Ent{l, 1.0, 0.0}; return 1; }
    if (m > 0) {
        double sgn = (m & 1) ? -1.0 : 1.0;
        e[0] = Ent{l + m, sgn * s2, 0.0};
        e[1] = Ent{l - m, 0.0, sgn * s2};
        return 2;
    }
    int mm = -m;
    e[0] = Ent{l + mm, s2, 0.0};
    e[1] = Ent{l - mm, 0.0, -s2};
    return 2;
}

constexpr Tables make_tables() {
    Tables T{};
    const int CL1[19]  = {0,0,0,1,1,1,1,1,1,1,2,2,2,2,2,2,2,2,2};
    const int CL2[19]  = {0,1,2,0,1,1,1,2,2,2,0,1,1,1,2,2,2,2,2};
    const int CL3[19]  = {0,1,2,1,0,1,2,1,2,3,2,1,2,3,0,1,2,3,4};
    const int COFF[19] = {0,1,10,35,44,53,80,125,170,245,350,375,420,495,600,625,700,825,1000};

    for (int c = 0; c < 19; ++c) {
        int l1 = CL1[c], l2 = CL2[c], l3 = CL3[c], coff = COFF[c];
        int n1 = 2 * l1 + 1, n2 = 2 * l2 + 1, n3 = 2 * l3 + 1, ntot = n1 * n2 * n3;
        double Cre[225] = {}, Cim[225] = {};
        for (int a = 0; a < n1; ++a)
            for (int b = 0; b < n2; ++b) {
                int m1 = a - l1, m2 = b - l2, m3 = -(m1 + m2);
                if (cabs_(m3) > l3) continue;
                double tv = cwig3j(l1, l2, l3, m1, m2, m3);
                if (tv == 0.0) continue;
                int crow = m3 + l3;
                Ent e1[2] = {}, e2[2] = {}, e3[2] = {};
                int k1 = arow(l1, a, e1), k2 = arow(l2, b, e2), k3 = arow(l3, crow, e3);
                for (int x = 0; x < k1; ++x)
                    for (int y = 0; y < k2; ++y)
                        for (int w = 0; w < k3; ++w) {
                            double r1 = e1[x].re, i1 = -e1[x].im;   // conj
                            double r2 = e2[y].re, i2 = -e2[y].im;
                            double r3 = e3[w].re, i3 = -e3[w].im;
                            double pr = r1 * r2 - i1 * i2, pi = r1 * i2 + i1 * r2;
                            double qr = pr * r3 - pi * i3, qi = pr * i3 + pi * r3;
                            int idx = (e1[x].col * n2 + e2[y].col) * n3 + e3[w].col;
                            Cre[idx] += tv * qr;
                            Cim[idx] += tv * qi;
                        }
            }
        double sR = 0.0, sI = 0.0;
        for (int i = 0; i < ntot; ++i) { sR += Cre[i] * Cre[i]; sI += Cim[i] * Cim[i]; }
        bool useRe = (sR >= sI);
        double nn = csqrt_(useRe ? sR : sI);
        double inv = nn > 0.0 ? 1.0 / nn : 0.0;
        for (int i = 0; i < ntot; ++i)
            T.cg[coff + i] = (float)((useRe ? Cre[i] : Cim[i]) * inv);
    }

    // W decode table: flat w -> (cg row offset, lf). Matches W layout order.
    const int NLFt[9]   = {1,1,1,1,3,3,1,3,5};
    const int CGOFF9[9] = {0,1,10,35,44,125,350,375,600};
    int w = 0;
    for (int ij = 0; ij < 9; ++ij) {
        int lo = ij / 3, li = ij % 3;
        int lfmin = lo > li ? lo - li : li - lo;
        int no2 = 2 * lo + 1, ni2 = 2 * li + 1, cgo = CGOFF9[ij];
        for (int k = 0; k < NLFt[ij]; ++k) {
            int lf = lfmin + k;
            for (int a = 0; a < no2; ++a)
                for (int b = 0; b < ni2; ++b) {
                    T.woff[w] = cgo + (a * ni2 + b) * (2 * lf + 1);
                    T.wlf[w]  = lf;
                    ++w;
                }
            cgo += no2 * ni2 * (2 * lf + 1);
        }
    }
    return T;
}

constexpr Tables H_TAB = make_tables();
__device__ __constant__ Tables d_tab = H_TAB;

// ---------------- main tensor-product kernel ----------------

// Per-column block compute: fixed (j, v, b) per thread; W cached in registers.
template <int LO, int LI, int NLF_>
__device__ __forceinline__ void do_block(const float* __restrict__ Wl,
                                         const float* __restrict__ Rl,
                                         float nrm, float* __restrict__ outcol,
                                         int v, int b, int woff, int roff, int rowbase) {
    constexpr int NO2 = 2 * LO + 1, NI2 = 2 * LI + 1;
    float Wreg[NLF_ * NO2];
#pragma unroll
    for (int k = 0; k < NLF_; ++k)
#pragma unroll
        for (int a = 0; a < NO2; ++a)
            Wreg[k * NO2 + a] = Wl[woff + (k * NO2 + a) * NI2 + b];
#pragma unroll 4
    for (int u = 0; u < 16; ++u) {
        int rb = roff + (u * 16 + v) * NLF_;
        float Rk[NLF_];
#pragma unroll
        for (int k = 0; k < NLF_; ++k) Rk[k] = Rl[rb + k];
        float* orow = outcol + (rowbase + u * NO2) * 144;
#pragma unroll
        for (int a = 0; a < NO2; ++a) {
            float acc = 0.f;
#pragma unroll
            for (int k = 0; k < NLF_; ++k) acc += Wreg[k * NO2 + a] * Rk[k];
            orow[a * 144] = nrm * acc;
        }
    }
}

__global__ __launch_bounds__(256) void tp_kernel(const float* __restrict__ Yg,
                                                 const float* __restrict__ Rg,
                                                 const float* __restrict__ Ng,
                                                 float* __restrict__ Og, int batch) {
    __shared__ __align__(16) float Rl[NPATH];
    __shared__ float Wl[NW];
    __shared__ float Ys[YDIM];

    int z = blockIdx.x;
    int t = threadIdx.x;

    // Stage R[z,:] coalesced as float4 (19456 B row, 16B-aligned).
    const float4* Rg4 = (const float4*)(Rg + (size_t)z * NPATH);
    float4* Rl4 = (float4*)Rl;
    for (int p = t; p < NPATH / 4; p += 256) Rl4[p] = Rg4[p];
    if (t < YDIM) Ys[t] = Yg[t * batch + z];   // Y is [25, batch]
    __syncthreads();

    // W[w] = sum_c cg[row_w, c] * Y[lf^2 + c, z]  (259 values)
    for (int w = t; w < NW; w += 256) {
        int off = d_tab.woff[w], lf = d_tab.wlf[w];
        float acc = 0.f;
        for (int ci = 0; ci <= 2 * lf; ++ci) acc += d_tab.cg[off + ci] * Ys[lf * lf + ci];
        Wl[w] = acc;
    }
    __syncthreads();

    // Wave-uniform column mapping: wave0 -> j=0 (16 cols), wave1 -> j=1 (48),
    // waves 2-3 -> j=2 (80). No intra-wave branch divergence.
    int j, v, b, col;
    if (t < 16)                     { j = 0; v = t; b = 0; col = t; }
    else if (t >= 64 && t < 112)    { int q = t - 64;  j = 1; v = q / 3; b = q - 3 * v; col = 16 + q; }
    else if (t >= 128 && t < 208)   { int q = t - 128; j = 2; v = q / 5; b = q - 5 * v; col = 64 + q; }
    else return;   // after last barrier; safe

    float* outcol = Og + (size_t)z * 20736 + col;
    float n0 = Ng[(0 * 3 + j) * batch + z];
    float n1 = Ng[(1 * 3 + j) * batch + z];
    float n2 = Ng[(2 * 3 + j) * batch + z];

    if (j == 0) {
        do_block<0, 0, 1>(Wl, Rl, n0, outcol, v, b,   0,    0,  0);
        do_block<1, 0, 1>(Wl, Rl, n1, outcol, v, b,   9,  768, 16);
        do_block<2, 0, 1>(Wl, Rl, n2, outcol, v, b,  84, 2560, 64);
    } else if (j == 1) {
        do_block<0, 1, 1>(Wl, Rl, n0, outcol, v, b,   1,  256,  0);
        do_block<1, 1, 3>(Wl, Rl, n1, outcol, v, b,  12, 1024, 16);
        do_block<2, 1, 3>(Wl, Rl, n2, outcol, v, b,  89, 2816, 64);
    } else {
        do_block<0, 2, 1>(Wl, Rl, n0, outcol, v, b,   4,  512,  0);
        do_block<1, 2, 3>(Wl, Rl, n1, outcol, v, b,  39, 1792, 16);
        do_block<2, 2, 5>(Wl, Rl, n2, outcol, v, b, 134, 3584, 64);
    }
}

extern "C" void kernel_launch(void* const* d_in, const int* in_sizes, int n_in,
                              void* d_out, int out_size, void* d_ws, size_t ws_size,
                              hipStream_t stream) {
    const float* Y = (const float*)d_in[0];
    const float* R = (const float*)d_in[1];
    const float* N = (const float*)d_in[2];
    float* O = (float*)d_out;
    int batch = in_sizes[0] / YDIM;   // 4096

    hipLaunchKernelGGL(tp_kernel, dim3(batch), dim3(256), 0, stream, Y, R, N, O, batch);
}